// Round 7
// baseline (324.438 us; speedup 1.0000x reference)
//
#include <hip/hip_runtime.h>
#include <hip/hip_bf16.h>
#include <stdint.h>

#define DMODEL 256
#define BATCH  16
#define MEL    2048
#define SRC    512
#define TB     16
#define SP2    2056   // attn P_lds row stride (bf16 units)

typedef __attribute__((ext_vector_type(8))) short bf16x8;
typedef __attribute__((ext_vector_type(4))) float f32x4;

__device__ inline short f2bf(float f) {
    union { float f; uint32_t u; } c{f};
    uint32_t u = c.u;
    u += 0x7FFFu + ((u >> 16) & 1u);   // RNE
    return (short)(u >> 16);
}

__device__ inline float bf2f(short s) {
    union { uint32_t u; float f; } c;
    c.u = ((uint32_t)(uint16_t)s) << 16;
    return c.f;
}

__device__ inline bf16x8 cvt8(const float* p) {
    const f32x4* q = reinterpret_cast<const f32x4*>(p);
    f32x4 a = q[0], b = q[1];
    bf16x8 r;
    r[0] = f2bf(a[0]); r[1] = f2bf(a[1]); r[2] = f2bf(a[2]); r[3] = f2bf(a[3]);
    r[4] = f2bf(b[0]); r[5] = f2bf(b[1]); r[6] = f2bf(b[2]); r[7] = f2bf(b[3]);
    return r;
}

// ---- convert Wq|Wk|Wv (each 256x256 f32) -> bf16, concatenated ----
__global__ __launch_bounds__(256)
void wconv_kernel(const float* __restrict__ Wq, const float* __restrict__ Wk,
                  const float* __restrict__ Wv, short* __restrict__ wb) {
    int i = blockIdx.x * 256 + threadIdx.x;
    int which = i >> 13;
    int off = (i & 8191) * 8;
    const float* src = which == 0 ? Wq : (which == 1 ? Wk : Wv);
    *reinterpret_cast<bf16x8*>(wb + which * 65536 + off) = cvt8(src + off);
}

// ---- unified projection kernel ----
// grid: 1152 blocks x 256 thr (4 waves). Units of equal MFMA work (128/wave):
//   u in [0,128)    : q-unit, 64 text rows (4 waves x 16 rows, 256 out cols)
//   u in [128,1152) : kv-unit, 32 mel rows; waves 0-1: K (16 rows x 256 cols),
//                     waves 2-3: V^T (128 vt-rows x 32 cols)
// B-operand (weights, L2-resident) double-buffered: bA/bB half-tiles (4x16B)
// prefetched one half ahead so L2 latency overlaps MFMA.
__global__ __launch_bounds__(256, 4)
void proj_all_kernel(const float* __restrict__ mel, const float* __restrict__ text,
                     const short* __restrict__ wb,
                     short* __restrict__ qbf, short* __restrict__ kbf,
                     short* __restrict__ vt) {
    __shared__ short SMEM[32 * 264];   // 16,896 B (kv staging)

    const short* Wqb = wb;
    const short* Wkb = wb + 65536;
    const short* Wvb = wb + 131072;

    const int tid = threadIdx.x;
    const int u = blockIdx.x;
    const int lane = tid & 63, w = tid >> 6;
    const int lr = lane & 15, lk = lane >> 4;

    if (u < 128) {
        // ---------- q-unit ----------
        // XCD-aware row remap: xcd = u&7 owns batches {2(u&7), 2(u&7)+1}
        const int up = ((u & 7) << 4) | (u >> 3);    // bijection 0..127
        const int row0 = up * 64 + w * 16;           // q-row base for this wave

        bf16x8 afr[8];
        const float* arow = text + (size_t)(row0 + lr) * DMODEL + 8 * lk;
#pragma unroll
        for (int t = 0; t < 8; ++t) afr[t] = cvt8(arow + 32 * t);

        bf16x8 bA[4], bB[4];
        auto LH = [&](bf16x8* d, int n, int h) {
            const short* p = Wqb + (size_t)(16 * n + lr) * DMODEL + 128 * h + 8 * lk;
#pragma unroll
            for (int j = 0; j < 4; ++j) d[j] = *reinterpret_cast<const bf16x8*>(p + 32 * j);
        };
        LH(bA, 0, 0);
#pragma unroll
        for (int n = 0; n < 16; ++n) {
            f32x4 acc = {0.f, 0.f, 0.f, 0.f};
            LH(bB, n, 1);
#pragma unroll
            for (int t = 0; t < 4; ++t)
                acc = __builtin_amdgcn_mfma_f32_16x16x32_bf16(afr[t], bA[t], acc, 0, 0, 0);
            if (n < 15) LH(bA, n + 1, 0);
#pragma unroll
            for (int t = 0; t < 4; ++t)
                acc = __builtin_amdgcn_mfma_f32_16x16x32_bf16(afr[4 + t], bB[t], acc, 0, 0, 0);
#pragma unroll
            for (int r = 0; r < 4; ++r)
                qbf[(size_t)(row0 + 4 * lk + r) * DMODEL + 16 * n + lr] = f2bf(acc[r]);
        }
        return;
    }

    // ---------- kv-unit ----------
    const int v = u - 128;
    const int xcd = v & 7;
    const int j = v >> 3;                 // 0..127
    const int b = 2 * xcd + (j >> 6);     // batch (XCD-local)
    const int mr0 = (j & 63) * 32;        // mel row base

    // stage 32 mel rows as bf16
    const float* gsrc = mel + (size_t)(b * MEL + mr0) * DMODEL;
#pragma unroll
    for (int i = 0; i < 4; ++i) {
        int c = i * 256 + tid;            // 1024 chunks of 8 elems
        int row = c >> 5, col = (c & 31) * 8;
        *reinterpret_cast<bf16x8*>(&SMEM[row * 264 + col]) = cvt8(gsrc + row * DMODEL + col);
    }
    __syncthreads();

    if (w < 2) {
        // K waves: mel rows [16w, 16w+16), all 256 out cols
        bf16x8 afr[8];
#pragma unroll
        for (int t = 0; t < 8; ++t)
            afr[t] = *reinterpret_cast<const bf16x8*>(&SMEM[(16 * w + lr) * 264 + 8 * lk + 32 * t]);

        bf16x8 bA[4], bB[4];
        auto LH = [&](bf16x8* d, int n, int h) {
            const short* p = Wkb + (size_t)(16 * n + lr) * DMODEL + 128 * h + 8 * lk;
#pragma unroll
            for (int jj = 0; jj < 4; ++jj) d[jj] = *reinterpret_cast<const bf16x8*>(p + 32 * jj);
        };
        LH(bA, 0, 0);
#pragma unroll
        for (int n = 0; n < 16; ++n) {
            f32x4 acc = {0.f, 0.f, 0.f, 0.f};
            LH(bB, n, 1);
#pragma unroll
            for (int t = 0; t < 4; ++t)
                acc = __builtin_amdgcn_mfma_f32_16x16x32_bf16(afr[t], bA[t], acc, 0, 0, 0);
            if (n < 15) LH(bA, n + 1, 0);
#pragma unroll
            for (int t = 0; t < 4; ++t)
                acc = __builtin_amdgcn_mfma_f32_16x16x32_bf16(afr[4 + t], bB[t], acc, 0, 0, 0);
#pragma unroll
            for (int r = 0; r < 4; ++r)
                kbf[(size_t)(b * MEL + mr0 + 16 * w + 4 * lk + r) * DMODEL + 16 * n + lr] =
                    f2bf(acc[r]);
        }
    } else {
        // V waves: vt rows [128*(w-2), +128), cols [mr0, mr0+32)
        const int w2 = w - 2;
#pragma unroll
        for (int m = 0; m < 8; ++m) {
            bf16x8 a2[8];
            const short* ar = Wvb + (size_t)(128 * w2 + 16 * m + lr) * DMODEL + 8 * lk;
#pragma unroll
            for (int t = 0; t < 8; ++t)
                a2[t] = *reinterpret_cast<const bf16x8*>(ar + 32 * t);
#pragma unroll
            for (int n = 0; n < 2; ++n) {
                f32x4 acc = {0.f, 0.f, 0.f, 0.f};
#pragma unroll
                for (int t = 0; t < 8; ++t) {
                    bf16x8 bfr = *reinterpret_cast<const bf16x8*>(
                        &SMEM[(16 * n + lr) * 264 + 8 * lk + 32 * t]);
                    acc = __builtin_amdgcn_mfma_f32_16x16x32_bf16(a2[t], bfr, acc, 0, 0, 0);
                }
#pragma unroll
                for (int r = 0; r < 4; ++r)
                    vt[(size_t)(b * DMODEL + 128 * w2 + 16 * m + 4 * lk + r) * MEL +
                       mr0 + 16 * n + lr] = f2bf(acc[r]);
            }
        }
    }
}

// ---- fused attention (unchanged from round 6) ----
__global__ __launch_bounds__(512, 4)
void attn_kernel(const short* __restrict__ qbf, const short* __restrict__ kbf,
                 const short* __restrict__ vt,
                 const int* __restrict__ mel_mask, const int* __restrict__ src_mask,
                 const float* __restrict__ gamma, const float* __restrict__ beta,
                 float* __restrict__ out, float* __restrict__ attn_out) {
    __shared__ short P[TB * SP2];     // 65,792 B
    __shared__ float red[2][TB][8];

    const int tid = threadIdx.x;
    const int lane = tid & 63, w = tid >> 6;
    const int lr = lane & 15, lk = lane >> 4;

    const int bid = blockIdx.x;
    const int idx = bid >> 3;
    const int b = 2 * (bid & 7) + (idx >> 5);
    const int t_base = (idx & 31) * TB;
    const int c0 = w * 256;

    bf16x8 qfr[8];
    const short* qrow = qbf + (size_t)(b * SRC + t_base + lr) * DMODEL + 8 * lk;
#pragma unroll
    for (int t = 0; t < 8; ++t)
        qfr[t] = *reinterpret_cast<const bf16x8*>(qrow + 32 * t);

    f32x4 acc[16];
#pragma unroll
    for (int tile = 0; tile < 16; ++tile) {
        f32x4 a = {0.f, 0.f, 0.f, 0.f};
        const short* krow = kbf + (size_t)(b * MEL + c0 + tile * 16 + lr) * DMODEL + 8 * lk;
#pragma unroll
        for (int t = 0; t < 8; ++t) {
            bf16x8 kfr = *reinterpret_cast<const bf16x8*>(krow + 32 * t);
            a = __builtin_amdgcn_mfma_f32_16x16x32_bf16(qfr[t], kfr, a, 0, 0, 0);
        }
        const bool masked = mel_mask[b * MEL + c0 + tile * 16 + lr] != 0;
#pragma unroll
        for (int r = 0; r < 4; ++r)
            acc[tile][r] = masked ? -1e30f : a[r] * 0.0625f;
    }

    float mr[4] = {-3.0e38f, -3.0e38f, -3.0e38f, -3.0e38f};
#pragma unroll
    for (int tile = 0; tile < 16; ++tile)
#pragma unroll
        for (int r = 0; r < 4; ++r) mr[r] = fmaxf(mr[r], acc[tile][r]);
#pragma unroll
    for (int off = 8; off; off >>= 1)
#pragma unroll
        for (int r = 0; r < 4; ++r) mr[r] = fmaxf(mr[r], __shfl_xor(mr[r], off));
    if (lr == 0) {
#pragma unroll
        for (int r = 0; r < 4; ++r) red[0][4 * lk + r][w] = mr[r];
    }
    __syncthreads();
    float M[4];
#pragma unroll
    for (int r = 0; r < 4; ++r) {
        float m = red[0][4 * lk + r][0];
#pragma unroll
        for (int jj = 1; jj < 8; ++jj) m = fmaxf(m, red[0][4 * lk + r][jj]);
        M[r] = m;
    }
    float sr[4] = {0.f, 0.f, 0.f, 0.f};
#pragma unroll
    for (int tile = 0; tile < 16; ++tile)
#pragma unroll
        for (int r = 0; r < 4; ++r) {
            float e = __expf(acc[tile][r] - M[r]);
            acc[tile][r] = e;
            sr[r] += e;
        }
#pragma unroll
    for (int off = 8; off; off >>= 1)
#pragma unroll
        for (int r = 0; r < 4; ++r) sr[r] += __shfl_xor(sr[r], off);
    if (lr == 0) {
#pragma unroll
        for (int r = 0; r < 4; ++r) red[1][4 * lk + r][w] = sr[r];
    }
    __syncthreads();
    float inv[4];
#pragma unroll
    for (int r = 0; r < 4; ++r) {
        float s = red[1][4 * lk + r][0];
#pragma unroll
        for (int jj = 1; jj < 8; ++jj) s += red[1][4 * lk + r][jj];
        inv[r] = src_mask[b * SRC + t_base + 4 * lk + r] ? 0.f : 1.f / s;
    }

#pragma unroll
    for (int tile = 0; tile < 16; ++tile) {
        const int col = c0 + tile * 16 + lr;
#pragma unroll
        for (int r = 0; r < 4; ++r)
            P[(4 * lk + r) * SP2 + col] = f2bf(acc[tile][r] * inv[r]);
    }
    __syncthreads();

    {
        float* abase = attn_out + (size_t)(b * SRC + t_base) * MEL;
        const int half = tid >> 8;
        const int c8 = (tid & 255) * 8;
#pragma unroll
        for (int it = 0; it < 8; ++it) {
            int row = 2 * it + half;
            bf16x8 p8 = *reinterpret_cast<const bf16x8*>(&P[row * SP2 + c8]);
            f32x4 lo = { bf2f(p8[0]), bf2f(p8[1]), bf2f(p8[2]), bf2f(p8[3]) };
            f32x4 hi = { bf2f(p8[4]), bf2f(p8[5]), bf2f(p8[6]), bf2f(p8[7]) };
            f32x4* g = reinterpret_cast<f32x4*>(abase + (size_t)row * MEL + c8);
            g[0] = lo;
            g[1] = hi;
        }
    }

    f32x4 pacc[2];
    pacc[0] = (f32x4){0.f, 0.f, 0.f, 0.f};
    pacc[1] = (f32x4){0.f, 0.f, 0.f, 0.f};
    for (int ks = 0; ks < MEL / 32; ++ks) {
        bf16x8 pa = *reinterpret_cast<const bf16x8*>(&P[lr * SP2 + 32 * ks + 8 * lk]);
#pragma unroll
        for (int n = 0; n < 2; ++n) {
            const short* vrow = vt + (size_t)(b * DMODEL + w * 32 + n * 16 + lr) * MEL +
                                32 * ks + 8 * lk;
            bf16x8 vfr = *reinterpret_cast<const bf16x8*>(vrow);
            pacc[n] = __builtin_amdgcn_mfma_f32_16x16x32_bf16(pa, vfr, pacc[n], 0, 0, 0);
        }
    }
    __syncthreads();

    float* O = reinterpret_cast<float*>(P);
#pragma unroll
    for (int n = 0; n < 2; ++n)
#pragma unroll
        for (int r = 0; r < 4; ++r)
            O[(4 * lk + r) * 264 + w * 32 + n * 16 + lr] = pacc[n][r];
    __syncthreads();

    {
        const int row = tid >> 5, l = tid & 31;
        const float* orow = O + row * 264;
        float s1 = 0.f;
#pragma unroll
        for (int jj = 0; jj < 8; ++jj) s1 += orow[l + 32 * jj];
#pragma unroll
        for (int off = 16; off; off >>= 1) s1 += __shfl_xor(s1, off);
        const float mu = s1 * (1.f / DMODEL);
        float s2 = 0.f;
#pragma unroll
        for (int jj = 0; jj < 8; ++jj) {
            float d = orow[l + 32 * jj] - mu;
            s2 += d * d;
        }
#pragma unroll
        for (int off = 16; off; off >>= 1) s2 += __shfl_xor(s2, off);
        const float rsig = rsqrtf(s2 * (1.f / DMODEL) + 1e-5f);
        float* g = out + (size_t)(b * SRC + t_base + row) * DMODEL;
#pragma unroll
        for (int jj = 0; jj < 8; ++jj) {
            int i = l + 32 * jj;
            g[i] = (orow[i] - mu) * rsig * gamma[i] + beta[i];
        }
    }
}

extern "C" void kernel_launch(void* const* d_in, const int* in_sizes, int n_in,
                              void* d_out, int out_size, void* d_ws, size_t ws_size,
                              hipStream_t stream) {
    const float* mel      = (const float*)d_in[0];
    const float* text     = (const float*)d_in[1];
    const int*   mel_mask = (const int*)d_in[2];
    const int*   src_mask = (const int*)d_in[3];
    const float* Wq       = (const float*)d_in[4];
    const float* Wk       = (const float*)d_in[5];
    const float* Wv       = (const float*)d_in[6];
    const float* gamma    = (const float*)d_in[7];
    const float* beta     = (const float*)d_in[8];

    float* out      = (float*)d_out;
    float* attn_out = out + (size_t)BATCH * SRC * DMODEL;

    short* wb  = (short*)d_ws;
    short* qbf = wb + 3 * 65536;
    short* kbf = qbf + (size_t)BATCH * SRC * DMODEL;
    short* vt  = kbf + (size_t)BATCH * MEL * DMODEL;

    wconv_kernel<<<96, 256, 0, stream>>>(Wq, Wk, Wv, wb);
    proj_all_kernel<<<1152, 256, 0, stream>>>(mel, text, wb, qbf, kbf, vt);
    attn_kernel<<<SRC / TB * BATCH, 512, 0, stream>>>(
        qbf, kbf, vt, mel_mask, src_mask, gamma, beta, out, attn_out);
}

// Round 8
// 238.978 us; speedup vs baseline: 1.3576x; 1.3576x over previous
//
#include <hip/hip_runtime.h>
#include <hip/hip_bf16.h>
#include <stdint.h>

#define DMODEL 256
#define BATCH  16
#define MEL    2048
#define SRC    512

typedef __attribute__((ext_vector_type(8))) short bf16x8;
typedef __attribute__((ext_vector_type(4))) float f32x4;
typedef __attribute__((ext_vector_type(4))) int   i32x4;

__device__ inline short f2bf(float f) {
    union { float f; uint32_t u; } c{f};
    uint32_t u = c.u;
    u += 0x7FFFu + ((u >> 16) & 1u);   // RNE
    return (short)(u >> 16);
}

__device__ inline bf16x8 cvt8(const float* p) {
    const f32x4* q = reinterpret_cast<const f32x4*>(p);
    f32x4 a = q[0], b = q[1];
    bf16x8 r;
    r[0] = f2bf(a[0]); r[1] = f2bf(a[1]); r[2] = f2bf(a[2]); r[3] = f2bf(a[3]);
    r[4] = f2bf(b[0]); r[5] = f2bf(b[1]); r[6] = f2bf(b[2]); r[7] = f2bf(b[3]);
    return r;
}

// ---- convert Wq|Wk|Wv (each 256x256 f32) -> bf16, concatenated ----
__global__ __launch_bounds__(256)
void wconv_kernel(const float* __restrict__ Wq, const float* __restrict__ Wk,
                  const float* __restrict__ Wv, short* __restrict__ wb) {
    int i = blockIdx.x * 256 + threadIdx.x;
    int which = i >> 13;
    int off = (i & 8191) * 8;
    const float* src = which == 0 ? Wq : (which == 1 ? Wk : Wv);
    *reinterpret_cast<bf16x8*>(wb + which * 65536 + off) = cvt8(src + off);
}

// ============================================================================
// Generic m97-style GEMM: C[M][N] = A[M][K] * Bt[N][K]^T   (row-major, K-contig)
// 128x128 tile, BK=64, 256 thr (4 waves, 2x2), reg-staged LDS (pad stride 72).
// grid = (M/128, N/128, Z); per-Z element strides aB/bB/cB.
// ============================================================================
template<bool AF32, bool BF32, bool CF32>
__global__ __launch_bounds__(256)
void gemm_bt(const void* __restrict__ Ap, const void* __restrict__ Bp,
             void* __restrict__ Cp, float scale, int K, int ldc,
             long aB, long bB, long cB) {
    __shared__ short As[128 * 72];
    __shared__ short Bs[128 * 72];

    const int tid = threadIdx.x;
    const int lane = tid & 63, w = tid >> 6;
    const int lr = lane & 15, lk = lane >> 4;
    const int wr = w >> 1, wc = w & 1;
    const size_t arow0 = (size_t)blockIdx.x * 128;
    const size_t brow0 = (size_t)blockIdx.y * 128;

    const char* Abase = (const char*)Ap + (size_t)blockIdx.z * aB * (AF32 ? 4 : 2);
    const char* Bbase = (const char*)Bp + (size_t)blockIdx.z * bB * (BF32 ? 4 : 2);
    char*       Cbase = (char*)Cp       + (size_t)blockIdx.z * cB * (CF32 ? 4 : 2);

    bf16x8 sA[4], sB[4];
    auto STAGE = [&](int kt) {
#pragma unroll
        for (int i = 0; i < 4; ++i) {
            int idx = i * 256 + tid;
            int row = idx >> 3, c8 = (idx & 7) * 8;
            size_t aoff = (arow0 + row) * (size_t)K + kt * 64 + c8;
            size_t boff = (brow0 + row) * (size_t)K + kt * 64 + c8;
            if constexpr (AF32) sA[i] = cvt8((const float*)Abase + aoff);
            else                sA[i] = *(const bf16x8*)((const short*)Abase + aoff);
            if constexpr (BF32) sB[i] = cvt8((const float*)Bbase + boff);
            else                sB[i] = *(const bf16x8*)((const short*)Bbase + boff);
        }
    };

    STAGE(0);
    f32x4 acc[4][4];
#pragma unroll
    for (int m = 0; m < 4; ++m)
#pragma unroll
        for (int n = 0; n < 4; ++n) acc[m][n] = (f32x4){0.f, 0.f, 0.f, 0.f};

    const int NK = K >> 6;
    for (int kt = 0; kt < NK; ++kt) {
        __syncthreads();
#pragma unroll
        for (int i = 0; i < 4; ++i) {
            int idx = i * 256 + tid;
            int row = idx >> 3, c8 = (idx & 7) * 8;
            *(bf16x8*)&As[row * 72 + c8] = sA[i];
            *(bf16x8*)&Bs[row * 72 + c8] = sB[i];
        }
        __syncthreads();
        if (kt + 1 < NK) STAGE(kt + 1);
#pragma unroll
        for (int kt2 = 0; kt2 < 2; ++kt2) {
            bf16x8 af[4], bfr[4];
#pragma unroll
            for (int m = 0; m < 4; ++m)
                af[m] = *(const bf16x8*)&As[(64 * wr + 16 * m + lr) * 72 + kt2 * 32 + 8 * lk];
#pragma unroll
            for (int n = 0; n < 4; ++n)
                bfr[n] = *(const bf16x8*)&Bs[(64 * wc + 16 * n + lr) * 72 + kt2 * 32 + 8 * lk];
#pragma unroll
            for (int m = 0; m < 4; ++m)
#pragma unroll
                for (int n = 0; n < 4; ++n)
                    acc[m][n] = __builtin_amdgcn_mfma_f32_16x16x32_bf16(af[m], bfr[n], acc[m][n], 0, 0, 0);
        }
    }

#pragma unroll
    for (int m = 0; m < 4; ++m)
#pragma unroll
        for (int n = 0; n < 4; ++n)
#pragma unroll
            for (int r = 0; r < 4; ++r) {
                size_t row = arow0 + 64 * wr + 16 * m + 4 * lk + r;
                size_t col = brow0 + 64 * wc + 16 * n + lr;
                if constexpr (CF32)
                    ((float*)Cbase)[row * ldc + col] = acc[m][n][r] * scale;
                else
                    ((short*)Cbase)[row * ldc + col] = f2bf(acc[m][n][r] * scale);
            }
}

// ---- in-place masked row softmax over attn [16*512 rows][2048] f32 ----
// one wave per row; mel-mask pre-softmax fill, src-mask post-softmax zero.
__global__ __launch_bounds__(512)
void softmax_kernel(float* __restrict__ attn, const int* __restrict__ mel_mask,
                    const int* __restrict__ src_mask) {
    const int w = threadIdx.x >> 6, lane = threadIdx.x & 63;
    const int row = blockIdx.x * 8 + w;          // 0..8191
    const int b = row >> 9, t = row & 511;
    float* p = attn + (size_t)row * MEL + lane * 32;
    const i32x4* mm = (const i32x4*)(mel_mask + b * MEL + lane * 32);

    f32x4 v[8]; i32x4 m[8];
#pragma unroll
    for (int j = 0; j < 8; ++j) { v[j] = ((const f32x4*)p)[j]; m[j] = mm[j]; }

    float mx = -3.0e38f;
#pragma unroll
    for (int j = 0; j < 8; ++j)
#pragma unroll
        for (int e = 0; e < 4; ++e) if (!m[j][e]) mx = fmaxf(mx, v[j][e]);
#pragma unroll
    for (int off = 32; off; off >>= 1) mx = fmaxf(mx, __shfl_xor(mx, off));

    float sum = 0.f;
#pragma unroll
    for (int j = 0; j < 8; ++j)
#pragma unroll
        for (int e = 0; e < 4; ++e) {
            float ev = m[j][e] ? 0.f : __expf(v[j][e] - mx);
            v[j][e] = ev; sum += ev;
        }
#pragma unroll
    for (int off = 32; off; off >>= 1) sum += __shfl_xor(sum, off);

    const float inv = src_mask[b * SRC + t] ? 0.f : 1.f / sum;
#pragma unroll
    for (int j = 0; j < 8; ++j) {
        f32x4 o = { v[j][0] * inv, v[j][1] * inv, v[j][2] * inv, v[j][3] * inv };
        ((f32x4*)p)[j] = o;
    }
}

// ---- PV GEMM + fused LayerNorm ----
// out[b][512][256] = attn[b][512][2048] x vt[b][256][2048]^T, then LN over dim 256.
// BM=64, BN=256(full N -> LN intra-wave), BK=64, 256 thr (4 waves, 16 rows each).
__global__ __launch_bounds__(256)
void pv_ln_kernel(const float* __restrict__ attn, const short* __restrict__ vt,
                  const float* __restrict__ gamma, const float* __restrict__ beta,
                  float* __restrict__ out) {
    __shared__ short As[64 * 72];
    __shared__ short Bs[256 * 72];

    const int tid = threadIdx.x;
    const int lane = tid & 63, w = tid >> 6;
    const int lr = lane & 15, lk = lane >> 4;
    const int b = blockIdx.y;
    const size_t row0 = (size_t)blockIdx.x * 64;
    const float* A = attn + (size_t)b * SRC * MEL;
    const short* B = vt + (size_t)b * DMODEL * MEL;

    float gm[16], bt[16];
#pragma unroll
    for (int n = 0; n < 16; ++n) { gm[n] = gamma[16 * n + lr]; bt[n] = beta[16 * n + lr]; }

    bf16x8 sA[2], sB[8];
    auto STAGE = [&](int kt) {
#pragma unroll
        for (int i = 0; i < 2; ++i) {
            int idx = i * 256 + tid; int row = idx >> 3, c8 = (idx & 7) * 8;
            sA[i] = cvt8(A + (row0 + row) * (size_t)MEL + kt * 64 + c8);
        }
#pragma unroll
        for (int i = 0; i < 8; ++i) {
            int idx = i * 256 + tid; int row = idx >> 3, c8 = (idx & 7) * 8;
            sB[i] = *(const bf16x8*)(B + row * (size_t)MEL + kt * 64 + c8);
        }
    };

    STAGE(0);
    f32x4 acc[16];
#pragma unroll
    for (int n = 0; n < 16; ++n) acc[n] = (f32x4){0.f, 0.f, 0.f, 0.f};

    for (int kt = 0; kt < MEL / 64; ++kt) {
        __syncthreads();
#pragma unroll
        for (int i = 0; i < 2; ++i) {
            int idx = i * 256 + tid;
            *(bf16x8*)&As[(idx >> 3) * 72 + (idx & 7) * 8] = sA[i];
        }
#pragma unroll
        for (int i = 0; i < 8; ++i) {
            int idx = i * 256 + tid;
            *(bf16x8*)&Bs[(idx >> 3) * 72 + (idx & 7) * 8] = sB[i];
        }
        __syncthreads();
        if (kt + 1 < MEL / 64) STAGE(kt + 1);
#pragma unroll
        for (int kt2 = 0; kt2 < 2; ++kt2) {
            bf16x8 af = *(const bf16x8*)&As[(16 * w + lr) * 72 + kt2 * 32 + 8 * lk];
#pragma unroll
            for (int n = 0; n < 16; ++n) {
                bf16x8 bfr = *(const bf16x8*)&Bs[(16 * n + lr) * 72 + kt2 * 32 + 8 * lk];
                acc[n] = __builtin_amdgcn_mfma_f32_16x16x32_bf16(af, bfr, acc[n], 0, 0, 0);
            }
        }
    }

    // LayerNorm: thread holds rows {4lk+r} x cols {16n+lr}; row = 16 lr-lanes x 16 n.
    float s1[4] = {0.f, 0.f, 0.f, 0.f};
#pragma unroll
    for (int n = 0; n < 16; ++n)
#pragma unroll
        for (int r = 0; r < 4; ++r) s1[r] += acc[n][r];
#pragma unroll
    for (int off = 8; off; off >>= 1)
#pragma unroll
        for (int r = 0; r < 4; ++r) s1[r] += __shfl_xor(s1[r], off);
    float mu[4];
#pragma unroll
    for (int r = 0; r < 4; ++r) mu[r] = s1[r] * (1.f / DMODEL);

    float s2[4] = {0.f, 0.f, 0.f, 0.f};
#pragma unroll
    for (int n = 0; n < 16; ++n)
#pragma unroll
        for (int r = 0; r < 4; ++r) {
            float d = acc[n][r] - mu[r];
            s2[r] += d * d;
        }
#pragma unroll
    for (int off = 8; off; off >>= 1)
#pragma unroll
        for (int r = 0; r < 4; ++r) s2[r] += __shfl_xor(s2[r], off);
    float rsig[4];
#pragma unroll
    for (int r = 0; r < 4; ++r) rsig[r] = rsqrtf(s2[r] * (1.f / DMODEL) + 1e-5f);

    float* orow = out + ((size_t)b * SRC + row0 + 16 * w) * DMODEL;
#pragma unroll
    for (int n = 0; n < 16; ++n)
#pragma unroll
        for (int r = 0; r < 4; ++r)
            orow[(4 * lk + r) * DMODEL + 16 * n + lr] =
                (acc[n][r] - mu[r]) * rsig[r] * gm[n] + bt[n];
}

extern "C" void kernel_launch(void* const* d_in, const int* in_sizes, int n_in,
                              void* d_out, int out_size, void* d_ws, size_t ws_size,
                              hipStream_t stream) {
    const float* mel      = (const float*)d_in[0];
    const float* text     = (const float*)d_in[1];
    const int*   mel_mask = (const int*)d_in[2];
    const int*   src_mask = (const int*)d_in[3];
    const float* Wq       = (const float*)d_in[4];
    const float* Wk       = (const float*)d_in[5];
    const float* Wv       = (const float*)d_in[6];
    const float* gamma    = (const float*)d_in[7];
    const float* beta     = (const float*)d_in[8];

    float* out  = (float*)d_out;
    float* attn = out + (size_t)BATCH * SRC * DMODEL;   // [16][512][2048] f32

    short* wb  = (short*)d_ws;                          // Wqb|Wkb|Wvb bf16
    short* qbf = wb + 3 * 65536;                        // [8192][256]
    short* kbf = qbf + (size_t)BATCH * SRC * DMODEL;    // [32768][256]
    short* vt  = kbf + (size_t)BATCH * MEL * DMODEL;    // [16][256][2048]

    wconv_kernel<<<96, 256, 0, stream>>>(Wq, Wk, Wv, wb);

    // q = text @ Wq^T   (M=8192, N=256, K=256)
    gemm_bt<true, false, false><<<dim3(64, 2, 1), 256, 0, stream>>>(
        text, wb, qbf, 1.f, 256, 256, 0, 0, 0);
    // k = mel @ Wk^T    (M=32768 flat, N=256, K=256)
    gemm_bt<true, false, false><<<dim3(256, 2, 1), 256, 0, stream>>>(
        mel, wb + 65536, kbf, 1.f, 256, 256, 0, 0, 0);
    // vt[b] = Wv @ mel[b]^T  (M=256, N=2048, K=256, per batch)
    gemm_bt<false, true, false><<<dim3(2, 16, BATCH), 256, 0, stream>>>(
        wb + 131072, mel, vt, 1.f, 256, 2048,
        0, (long)MEL * DMODEL, (long)DMODEL * MEL);
    // S[b] = q[b] @ k[b]^T / 16 -> attn (f32)  (M=512, N=2048, K=256, per batch)
    gemm_bt<false, false, true><<<dim3(4, 16, BATCH), 256, 0, stream>>>(
        qbf, kbf, attn, 0.0625f, 256, 2048,
        (long)SRC * DMODEL, (long)MEL * DMODEL, (long)SRC * MEL);

    softmax_kernel<<<BATCH * SRC / 8, 512, 0, stream>>>(attn, mel_mask, src_mask);

    pv_ln_kernel<<<dim3(SRC / 64, BATCH), 256, 0, stream>>>(
        attn, vt, gamma, beta, out);
}

// Round 9
// 225.092 us; speedup vs baseline: 1.4414x; 1.0617x over previous
//
#include <hip/hip_runtime.h>
#include <hip/hip_bf16.h>
#include <stdint.h>

#define DMODEL 256
#define BATCH  16
#define MEL    2048
#define SRC    512

typedef __attribute__((ext_vector_type(8))) short bf16x8;
typedef __attribute__((ext_vector_type(4))) short short4v;
typedef __attribute__((ext_vector_type(4))) float f32x4;
typedef __attribute__((ext_vector_type(4))) int   i32x4;

__device__ inline short f2bf(float f) {
    union { float f; uint32_t u; } c{f};
    uint32_t u = c.u;
    u += 0x7FFFu + ((u >> 16) & 1u);   // RNE
    return (short)(u >> 16);
}

__device__ inline bf16x8 cvt8(const float* p) {
    const f32x4* q = reinterpret_cast<const f32x4*>(p);
    f32x4 a = q[0], b = q[1];
    bf16x8 r;
    r[0] = f2bf(a[0]); r[1] = f2bf(a[1]); r[2] = f2bf(a[2]); r[3] = f2bf(a[3]);
    r[4] = f2bf(b[0]); r[5] = f2bf(b[1]); r[6] = f2bf(b[2]); r[7] = f2bf(b[7-4]); // placeholder fixed below
    r[7] = f2bf(b[3]);
    r[6] = f2bf(b[2]);
    return r;
}

// ============================================================================
// proj_all: all three projections as 128x128x256 tile-units, f32 in, bf16 out.
//   u <  128 : q  = text @ Wq^T   (64 M-tiles x 2 N-tiles)
//   u <  640 : k  = mel  @ Wk^T   (256 x 2)
//   u >= 640 : vt[b] = Wv @ mel[b]^T  (2 x 16 x 16 batches, XCD-affine)
// ============================================================================
__global__ __launch_bounds__(256)
void proj_all_kernel(const float* __restrict__ mel, const float* __restrict__ text,
                     const float* __restrict__ Wq, const float* __restrict__ Wk,
                     const float* __restrict__ Wv,
                     short* __restrict__ qbf, short* __restrict__ kbf,
                     short* __restrict__ vt) {
    __shared__ char SMEM[36864];                 // As|Bs (2x128x72 short); C-stage alias
    short* As = (short*)SMEM;
    short* Bs = (short*)SMEM + 128 * 72;

    const int tid = threadIdx.x;
    const int lane = tid & 63, w = tid >> 6;
    const int lr = lane & 15, lk = lane >> 4;
    const int wr = w >> 1, wc = w & 1;

    const int u = blockIdx.x;
    const float *Af, *Bf; short* C; int ldc; size_t arow0, brow0;
    if (u < 128) {
        arow0 = (size_t)(u >> 1) * 128; brow0 = (size_t)(u & 1) * 128;
        Af = text; Bf = Wq; C = qbf; ldc = DMODEL;
    } else if (u < 640) {
        int v = u - 128;
        arow0 = (size_t)(v >> 1) * 128; brow0 = (size_t)(v & 1) * 128;
        Af = mel; Bf = Wk; C = kbf; ldc = DMODEL;
    } else {
        int v = u - 640;
        int xcd = v & 7, j = v >> 3;
        int b = 2 * xcd + (j >> 5), t = j & 31;
        arow0 = (size_t)(t & 1) * 128; brow0 = (size_t)(t >> 1) * 128;
        Af = Wv; Bf = mel + (size_t)b * MEL * DMODEL;
        C = vt + (size_t)b * DMODEL * MEL; ldc = MEL;
    }
    C += arow0 * ldc + brow0;

    bf16x8 sA[4], sB[4];
    auto STAGE = [&](int kt) {
#pragma unroll
        for (int i = 0; i < 4; ++i) {
            int idx = i * 256 + tid;
            int row = idx >> 3, c8 = (idx & 7) * 8;
            sA[i] = cvt8(Af + (arow0 + row) * 256 + kt * 64 + c8);
            sB[i] = cvt8(Bf + (brow0 + row) * 256 + kt * 64 + c8);
        }
    };

    STAGE(0);
    f32x4 acc[4][4];
#pragma unroll
    for (int m = 0; m < 4; ++m)
#pragma unroll
        for (int n = 0; n < 4; ++n) acc[m][n] = (f32x4){0.f, 0.f, 0.f, 0.f};

    for (int kt = 0; kt < 4; ++kt) {
        __syncthreads();
#pragma unroll
        for (int i = 0; i < 4; ++i) {
            int idx = i * 256 + tid;
            int row = idx >> 3, c8 = (idx & 7) * 8;
            *(bf16x8*)&As[row * 72 + c8] = sA[i];
            *(bf16x8*)&Bs[row * 72 + c8] = sB[i];
        }
        __syncthreads();
        if (kt < 3) STAGE(kt + 1);
#pragma unroll
        for (int kt2 = 0; kt2 < 2; ++kt2) {
            bf16x8 af[4], bfr[4];
#pragma unroll
            for (int m = 0; m < 4; ++m)
                af[m] = *(const bf16x8*)&As[(64 * wr + 16 * m + lr) * 72 + kt2 * 32 + 8 * lk];
#pragma unroll
            for (int n = 0; n < 4; ++n)
                bfr[n] = *(const bf16x8*)&Bs[(64 * wc + 16 * n + lr) * 72 + kt2 * 32 + 8 * lk];
#pragma unroll
            for (int m = 0; m < 4; ++m)
#pragma unroll
                for (int n = 0; n < 4; ++n)
                    acc[m][n] = __builtin_amdgcn_mfma_f32_16x16x32_bf16(af[m], bfr[n], acc[m][n], 0, 0, 0);
        }
    }

    // C epilogue: stage bf16 tile [128][136] in LDS, then coalesced row writes
    __syncthreads();
    short* Cs = (short*)SMEM;
#pragma unroll
    for (int m = 0; m < 4; ++m)
#pragma unroll
        for (int n = 0; n < 4; ++n)
#pragma unroll
            for (int r = 0; r < 4; ++r)
                Cs[(64 * wr + 16 * m + 4 * lk + r) * 136 + 64 * wc + 16 * n + lr] =
                    f2bf(acc[m][n][r]);
    __syncthreads();
#pragma unroll
    for (int i = 0; i < 8; ++i) {
        int idx = i * 256 + tid;
        int row = idx >> 4, c8 = (idx & 15) * 8;
        *(bf16x8*)&C[(size_t)row * ldc + c8] = *(const bf16x8*)&Cs[row * 136 + c8];
    }
}

// ============================================================================
// sgemm: S[b] = q[b] @ k[b]^T * 1/16 -> attn f32.  bf16 in, f32 out.
// grid 1024 (XCD-affine: xcd owns batches {2x,2x+1}); 128x128 tile, BK=64.
// ============================================================================
__global__ __launch_bounds__(256)
void sgemm_kernel(const short* __restrict__ qbf, const short* __restrict__ kbf,
                  float* __restrict__ attn) {
    __shared__ char SMEM[36864];
    short* As = (short*)SMEM;
    short* Bs = (short*)SMEM + 128 * 72;

    const int tid = threadIdx.x;
    const int lane = tid & 63, w = tid >> 6;
    const int lr = lane & 15, lk = lane >> 4;
    const int wr = w >> 1, wc = w & 1;

    const int bid = blockIdx.x;
    const int xcd = bid & 7, j = bid >> 3;
    const int z = 2 * xcd + (j >> 6);
    const int t = j & 63;
    const int x = t & 3, y = t >> 2;

    const short* A = qbf + (size_t)z * SRC * DMODEL + (size_t)x * 128 * DMODEL;
    const short* B = kbf + (size_t)z * MEL * DMODEL + (size_t)y * 128 * DMODEL;
    float* Cw = attn + (size_t)z * SRC * MEL + (size_t)x * 128 * MEL + (size_t)y * 128;

    bf16x8 sA[4], sB[4];
    auto STAGE = [&](int kt) {
#pragma unroll
        for (int i = 0; i < 4; ++i) {
            int idx = i * 256 + tid;
            int row = idx >> 3, c8 = (idx & 7) * 8;
            sA[i] = *(const bf16x8*)(A + (size_t)row * DMODEL + kt * 64 + c8);
            sB[i] = *(const bf16x8*)(B + (size_t)row * DMODEL + kt * 64 + c8);
        }
    };

    STAGE(0);
    f32x4 acc[4][4];
#pragma unroll
    for (int m = 0; m < 4; ++m)
#pragma unroll
        for (int n = 0; n < 4; ++n) acc[m][n] = (f32x4){0.f, 0.f, 0.f, 0.f};

    for (int kt = 0; kt < 4; ++kt) {
        __syncthreads();
#pragma unroll
        for (int i = 0; i < 4; ++i) {
            int idx = i * 256 + tid;
            int row = idx >> 3, c8 = (idx & 7) * 8;
            *(bf16x8*)&As[row * 72 + c8] = sA[i];
            *(bf16x8*)&Bs[row * 72 + c8] = sB[i];
        }
        __syncthreads();
        if (kt < 3) STAGE(kt + 1);
#pragma unroll
        for (int kt2 = 0; kt2 < 2; ++kt2) {
            bf16x8 af[4], bfr[4];
#pragma unroll
            for (int m = 0; m < 4; ++m)
                af[m] = *(const bf16x8*)&As[(64 * wr + 16 * m + lr) * 72 + kt2 * 32 + 8 * lk];
#pragma unroll
            for (int n = 0; n < 4; ++n)
                bfr[n] = *(const bf16x8*)&Bs[(64 * wc + 16 * n + lr) * 72 + kt2 * 32 + 8 * lk];
#pragma unroll
            for (int m = 0; m < 4; ++m)
#pragma unroll
                for (int n = 0; n < 4; ++n)
                    acc[m][n] = __builtin_amdgcn_mfma_f32_16x16x32_bf16(af[m], bfr[n], acc[m][n], 0, 0, 0);
        }
    }

    // f32 epilogue via LDS, two 64-row halves (64x132 f32 = 33.8 KB)
    __syncthreads();
    float* Cs = (float*)SMEM;
#pragma unroll
    for (int half = 0; half < 2; ++half) {
        if (wr == half) {
#pragma unroll
            for (int m = 0; m < 4; ++m)
#pragma unroll
                for (int n = 0; n < 4; ++n)
#pragma unroll
                    for (int r = 0; r < 4; ++r)
                        Cs[(16 * m + 4 * lk + r) * 132 + 64 * wc + 16 * n + lr] =
                            acc[m][n][r] * 0.0625f;
        }
        __syncthreads();
#pragma unroll
        for (int i = 0; i < 8; ++i) {
            int idx = i * 256 + tid;
            int row = idx >> 5, c4 = (idx & 31) * 4;
            *(f32x4*)&Cw[(size_t)(half * 64 + row) * MEL + c4] = *(const f32x4*)&Cs[row * 132 + c4];
        }
        __syncthreads();
    }
}

// ---- in-place masked row softmax over attn [8192 rows][2048] f32 ----
__global__ __launch_bounds__(512)
void softmax_kernel(float* __restrict__ attn, const int* __restrict__ mel_mask,
                    const int* __restrict__ src_mask) {
    const int w = threadIdx.x >> 6, lane = threadIdx.x & 63;
    const int row = blockIdx.x * 8 + w;
    const int b = row >> 9, t = row & 511;
    float* p = attn + (size_t)row * MEL + lane * 32;
    const i32x4* mm = (const i32x4*)(mel_mask + b * MEL + lane * 32);

    f32x4 v[8]; i32x4 m[8];
#pragma unroll
    for (int j = 0; j < 8; ++j) { v[j] = ((const f32x4*)p)[j]; m[j] = mm[j]; }

    float mx = -3.0e38f;
#pragma unroll
    for (int j = 0; j < 8; ++j)
#pragma unroll
        for (int e = 0; e < 4; ++e) if (!m[j][e]) mx = fmaxf(mx, v[j][e]);
#pragma unroll
    for (int off = 32; off; off >>= 1) mx = fmaxf(mx, __shfl_xor(mx, off));

    float sum = 0.f;
#pragma unroll
    for (int j = 0; j < 8; ++j)
#pragma unroll
        for (int e = 0; e < 4; ++e) {
            float ev = m[j][e] ? 0.f : __expf(v[j][e] - mx);
            v[j][e] = ev; sum += ev;
        }
#pragma unroll
    for (int off = 32; off; off >>= 1) sum += __shfl_xor(sum, off);

    const float inv = src_mask[b * SRC + t] ? 0.f : 1.f / sum;
#pragma unroll
    for (int j = 0; j < 8; ++j) {
        f32x4 o = { v[j][0] * inv, v[j][1] * inv, v[j][2] * inv, v[j][3] * inv };
        ((f32x4*)p)[j] = o;
    }
}

// ============================================================================
// pv_ln: out[b] = LN(attn[b] @ vt[b]^T).  BM=32, BN=256 (full row), BK=64.
// 512 thr = 8 waves (2 M x 4 N); grid 256, XCD-affine. LN fused, coalesced out.
// ============================================================================
__global__ __launch_bounds__(512)
void pv_ln_kernel(const float* __restrict__ attn, const short* __restrict__ vt,
                  const float* __restrict__ gamma, const float* __restrict__ beta,
                  float* __restrict__ out) {
    __shared__ char SMEM[42496];
    short* As = (short*)SMEM;                    // [32][72]
    short* Bs = (short*)(SMEM + 4608);           // [256][72]
    float* red = (float*)(SMEM + 41472);         // [2][32][4]
    float* Ost = (float*)(SMEM + 4608);          // [32][260] (aliases Bs)

    const int tid = threadIdx.x;
    const int lane = tid & 63, w = tid >> 6;
    const int lr = lane & 15, lk = lane >> 4;
    const int wr = w >> 2, wc = w & 3;

    const int bid = blockIdx.x;
    const int xcd = bid & 7, j = bid >> 3;
    const int b = 2 * xcd + (j >> 4);
    const int mt = j & 15;
    const size_t row0 = (size_t)mt * 32;

    const float* A = attn + (size_t)b * SRC * MEL + row0 * MEL;
    const short* Bv = vt + (size_t)b * DMODEL * MEL;

    float gm[4], bt[4];
#pragma unroll
    for (int n = 0; n < 4; ++n) {
        gm[n] = gamma[64 * wc + 16 * n + lr];
        bt[n] = beta[64 * wc + 16 * n + lr];
    }

    // staging regs
    f32x4 sAv; bf16x8 sB[4];
    const int a_row = tid >> 4, a_c4 = (tid & 15) * 4;
    auto STAGE = [&](int kt) {
        sAv = *(const f32x4*)(A + (size_t)a_row * MEL + kt * 64 + a_c4);
#pragma unroll
        for (int i = 0; i < 4; ++i) {
            int idx = i * 512 + tid;
            int row = idx >> 3, c8 = (idx & 7) * 8;
            sB[i] = *(const bf16x8*)(Bv + (size_t)row * MEL + kt * 64 + c8);
        }
    };

    STAGE(0);
    f32x4 acc[4];
#pragma unroll
    for (int n = 0; n < 4; ++n) acc[n] = (f32x4){0.f, 0.f, 0.f, 0.f};

    for (int kt = 0; kt < MEL / 64; ++kt) {
        __syncthreads();
        {
            short4v a4 = { f2bf(sAv[0]), f2bf(sAv[1]), f2bf(sAv[2]), f2bf(sAv[3]) };
            *(short4v*)&As[a_row * 72 + a_c4] = a4;
#pragma unroll
            for (int i = 0; i < 4; ++i) {
                int idx = i * 512 + tid;
                int row = idx >> 3, c8 = (idx & 7) * 8;
                *(bf16x8*)&Bs[row * 72 + c8] = sB[i];
            }
        }
        __syncthreads();
        if (kt + 1 < MEL / 64) STAGE(kt + 1);
#pragma unroll
        for (int kt2 = 0; kt2 < 2; ++kt2) {
            bf16x8 af = *(const bf16x8*)&As[(16 * wr + lr) * 72 + kt2 * 32 + 8 * lk];
#pragma unroll
            for (int n = 0; n < 4; ++n) {
                bf16x8 bfr = *(const bf16x8*)&Bs[(64 * wc + 16 * n + lr) * 72 + kt2 * 32 + 8 * lk];
                acc[n] = __builtin_amdgcn_mfma_f32_16x16x32_bf16(af, bfr, acc[n], 0, 0, 0);
            }
        }
    }

    // LayerNorm: thread holds rows {16wr+4lk+r}, cols {64wc+16n+lr}
    float s1[4] = {0.f, 0.f, 0.f, 0.f}, s2[4] = {0.f, 0.f, 0.f, 0.f};
#pragma unroll
    for (int n = 0; n < 4; ++n)
#pragma unroll
        for (int r = 0; r < 4; ++r) {
            s1[r] += acc[n][r];
            s2[r] += acc[n][r] * acc[n][r];
        }
#pragma unroll
    for (int off = 8; off; off >>= 1)
#pragma unroll
        for (int r = 0; r < 4; ++r) {
            s1[r] += __shfl_xor(s1[r], off);
            s2[r] += __shfl_xor(s2[r], off);
        }
    __syncthreads();   // Bs MFMA reads done; red region safe
    if (lr == 0) {
#pragma unroll
        for (int r = 0; r < 4; ++r) {
            red[(16 * wr + 4 * lk + r) * 4 + wc] = s1[r];
            red[128 + (16 * wr + 4 * lk + r) * 4 + wc] = s2[r];
        }
    }
    __syncthreads();
    float mu[4], rsig[4];
#pragma unroll
    for (int r = 0; r < 4; ++r) {
        int rowi = 16 * wr + 4 * lk + r;
        float S1 = red[rowi * 4 + 0] + red[rowi * 4 + 1] + red[rowi * 4 + 2] + red[rowi * 4 + 3];
        float S2 = red[128 + rowi * 4 + 0] + red[128 + rowi * 4 + 1] +
                   red[128 + rowi * 4 + 2] + red[128 + rowi * 4 + 3];
        mu[r] = S1 * (1.f / DMODEL);
        rsig[r] = rsqrtf(S2 * (1.f / DMODEL) - mu[r] * mu[r] + 1e-5f);
    }
    __syncthreads();   // before overwriting Bs region with Ost
#pragma unroll
    for (int n = 0; n < 4; ++n)
#pragma unroll
        for (int r = 0; r < 4; ++r)
            Ost[(16 * wr + 4 * lk + r) * 260 + 64 * wc + 16 * n + lr] =
                (acc[n][r] - mu[r]) * rsig[r] * gm[n] + bt[n];
    __syncthreads();
#pragma unroll
    for (int i = 0; i < 4; ++i) {
        int idx = i * 512 + tid;
        int row = idx >> 6, c4 = (idx & 63) * 4;
        *(f32x4*)&out[((size_t)b * SRC + row0 + row) * DMODEL + c4] =
            *(const f32x4*)&Ost[row * 260 + c4];
    }
}

extern "C" void kernel_launch(void* const* d_in, const int* in_sizes, int n_in,
                              void* d_out, int out_size, void* d_ws, size_t ws_size,
                              hipStream_t stream) {
    const float* mel      = (const float*)d_in[0];
    const float* text     = (const float*)d_in[1];
    const int*   mel_mask = (const int*)d_in[2];
    const int*   src_mask = (const int*)d_in[3];
    const float* Wq       = (const float*)d_in[4];
    const float* Wk       = (const float*)d_in[5];
    const float* Wv       = (const float*)d_in[6];
    const float* gamma    = (const float*)d_in[7];
    const float* beta     = (const float*)d_in[8];

    float* out  = (float*)d_out;
    float* attn = out + (size_t)BATCH * SRC * DMODEL;   // [16][512][2048] f32

    short* qbf = (short*)d_ws;                          // [8192][256] bf16
    short* kbf = qbf + (size_t)BATCH * SRC * DMODEL;    // [32768][256] bf16
    short* vt  = kbf + (size_t)BATCH * MEL * DMODEL;    // [16][256][2048] bf16

    proj_all_kernel<<<1152, 256, 0, stream>>>(mel, text, Wq, Wk, Wv, qbf, kbf, vt);
    sgemm_kernel<<<1024, 256, 0, stream>>>(qbf, kbf, attn);
    softmax_kernel<<<BATCH * SRC / 8, 512, 0, stream>>>(attn, mel_mask, src_mask);
    pv_ln_kernel<<<256, 512, 0, stream>>>(attn, vt, gamma, beta, out);
}

// Round 10
// 202.881 us; speedup vs baseline: 1.5992x; 1.1095x over previous
//
#include <hip/hip_runtime.h>
#include <hip/hip_bf16.h>
#include <stdint.h>

#define DMODEL 256
#define BATCH  16
#define MEL    2048
#define SRC    512

typedef __attribute__((ext_vector_type(8))) short bf16x8;
typedef __attribute__((ext_vector_type(4))) short short4v;
typedef __attribute__((ext_vector_type(4))) float f32x4;

__device__ inline short f2bf(float f) {
    union { float f; uint32_t u; } c{f};
    uint32_t u = c.u;
    u += 0x7FFFu + ((u >> 16) & 1u);   // RNE
    return (short)(u >> 16);
}

__device__ inline bf16x8 cvt8(const float* p) {
    const f32x4* q = reinterpret_cast<const f32x4*>(p);
    f32x4 a = q[0], b = q[1];
    bf16x8 r;
    r[0] = f2bf(a[0]); r[1] = f2bf(a[1]); r[2] = f2bf(a[2]); r[3] = f2bf(a[3]);
    r[4] = f2bf(b[0]); r[5] = f2bf(b[1]); r[6] = f2bf(b[2]); r[7] = f2bf(b[3]);
    return r;
}

// ============================================================================
// proj_all: q/k/vt as 128x128x256 tile-units, f32 in, bf16 out.
// Unit decode is XCD-affine AND stripe-grouped: xcd = u&7, slot = u>>3.
//   slot <128 : kv-unit. g=slot>>2 -> stripe st=32*xcd+g (128 mel rows);
//               m=slot&3: m<2 k-tile (N-half m), m>=2 vt-tile (M-half m-2).
//               The 4 units of a stripe are co-resident on one XCD -> mel
//               stripe read once from HBM, 2nd use hits L2.
//   slot>=128 : q-unit qi=16*xcd+(slot-128) -> batches {2xcd,2xcd+1}.
// ============================================================================
__global__ __launch_bounds__(256)
void proj_all_kernel(const float* __restrict__ mel, const float* __restrict__ text,
                     const float* __restrict__ Wq, const float* __restrict__ Wk,
                     const float* __restrict__ Wv,
                     short* __restrict__ qbf, short* __restrict__ kbf,
                     short* __restrict__ vt) {
    __shared__ char SMEM[36864];                 // As|Bs (2x128x72 short); C-stage alias
    short* As = (short*)SMEM;
    short* Bs = (short*)SMEM + 128 * 72;

    const int tid = threadIdx.x;
    const int lane = tid & 63, w = tid >> 6;
    const int lr = lane & 15, lk = lane >> 4;
    const int wr = w >> 1, wc = w & 1;

    const int u = blockIdx.x;
    const int xcd = u & 7, slot = u >> 3;

    const float *Af, *Bf; short* C; int ldc;
    size_t aro, bro, coff;
    if (slot < 128) {
        const int g = slot >> 2, m = slot & 3;
        const int st = 32 * xcd + g;             // 0..255
        const int b = st >> 4;
        const size_t mr0 = (size_t)(st & 15) * 128;
        if (m < 2) {             // k-tile
            aro = (size_t)b * MEL + mr0;
            bro = (size_t)m * 128;
            Af = mel; Bf = Wk; C = kbf; ldc = DMODEL;
            coff = aro * DMODEL + bro;
        } else {                 // vt-tile
            aro = (size_t)(m - 2) * 128;
            bro = (size_t)b * MEL + mr0;
            Af = Wv; Bf = mel; C = vt + (size_t)b * DMODEL * MEL; ldc = MEL;
            coff = aro * MEL + mr0;
        }
    } else {
        const int qi = 16 * xcd + (slot - 128);  // 0..127
        aro = (size_t)(qi >> 1) * 128;
        bro = (size_t)(qi & 1) * 128;
        Af = text; Bf = Wq; C = qbf; ldc = DMODEL;
        coff = aro * DMODEL + bro;
    }
    C += coff;

    bf16x8 sA[4], sB[4];
    auto STAGE = [&](int kt) {
#pragma unroll
        for (int i = 0; i < 4; ++i) {
            int idx = i * 256 + tid;
            int row = idx >> 3, c8 = (idx & 7) * 8;
            sA[i] = cvt8(Af + (aro + row) * 256 + kt * 64 + c8);
            sB[i] = cvt8(Bf + (bro + row) * 256 + kt * 64 + c8);
        }
    };

    STAGE(0);
    f32x4 acc[4][4];
#pragma unroll
    for (int m = 0; m < 4; ++m)
#pragma unroll
        for (int n = 0; n < 4; ++n) acc[m][n] = (f32x4){0.f, 0.f, 0.f, 0.f};

    for (int kt = 0; kt < 4; ++kt) {
        __syncthreads();
#pragma unroll
        for (int i = 0; i < 4; ++i) {
            int idx = i * 256 + tid;
            int row = idx >> 3, c8 = (idx & 7) * 8;
            *(bf16x8*)&As[row * 72 + c8] = sA[i];
            *(bf16x8*)&Bs[row * 72 + c8] = sB[i];
        }
        __syncthreads();
        if (kt < 3) STAGE(kt + 1);
#pragma unroll
        for (int kt2 = 0; kt2 < 2; ++kt2) {
            bf16x8 af[4], bfr[4];
#pragma unroll
            for (int m = 0; m < 4; ++m)
                af[m] = *(const bf16x8*)&As[(64 * wr + 16 * m + lr) * 72 + kt2 * 32 + 8 * lk];
#pragma unroll
            for (int n = 0; n < 4; ++n)
                bfr[n] = *(const bf16x8*)&Bs[(64 * wc + 16 * n + lr) * 72 + kt2 * 32 + 8 * lk];
#pragma unroll
            for (int m = 0; m < 4; ++m)
#pragma unroll
                for (int n = 0; n < 4; ++n)
                    acc[m][n] = __builtin_amdgcn_mfma_f32_16x16x32_bf16(af[m], bfr[n], acc[m][n], 0, 0, 0);
        }
    }

    // C epilogue: stage bf16 tile [128][136] in LDS, then coalesced row writes
    __syncthreads();
    short* Cs = (short*)SMEM;
#pragma unroll
    for (int m = 0; m < 4; ++m)
#pragma unroll
        for (int n = 0; n < 4; ++n)
#pragma unroll
            for (int r = 0; r < 4; ++r)
                Cs[(64 * wr + 16 * m + 4 * lk + r) * 136 + 64 * wc + 16 * n + lr] =
                    f2bf(acc[m][n][r]);
    __syncthreads();
#pragma unroll
    for (int i = 0; i < 8; ++i) {
        int idx = i * 256 + tid;
        int row = idx >> 4, c8 = (idx & 15) * 8;
        *(bf16x8*)&C[(size_t)row * ldc + c8] = *(const bf16x8*)&Cs[row * 136 + c8];
    }
}

// ============================================================================
// sgemm: S[b] = q[b] @ k[b]^T / 16, mel-masked, -> attn f32.
// Also emits per-(row, 128-col-block) softmax partials (max, sum-exp).
// grid 1024, XCD-affine.
// ============================================================================
__global__ __launch_bounds__(256)
void sgemm_kernel(const short* __restrict__ qbf, const short* __restrict__ kbf,
                  const int* __restrict__ mel_mask,
                  float* __restrict__ attn,
                  float* __restrict__ pmax, float* __restrict__ psum) {
    __shared__ char SMEM[36864];
    short* As = (short*)SMEM;
    short* Bs = (short*)SMEM + 128 * 72;

    const int tid = threadIdx.x;
    const int lane = tid & 63, w = tid >> 6;
    const int lr = lane & 15, lk = lane >> 4;
    const int wr = w >> 1, wc = w & 1;

    const int bid = blockIdx.x;
    const int xcd = bid & 7, j = bid >> 3;
    const int z = 2 * xcd + (j >> 6);
    const int t = j & 63;
    const int x = t & 3, y = t >> 2;

    const short* A = qbf + (size_t)z * SRC * DMODEL + (size_t)x * 128 * DMODEL;
    const short* B = kbf + (size_t)z * MEL * DMODEL + (size_t)y * 128 * DMODEL;
    float* Cw = attn + (size_t)z * SRC * MEL + (size_t)x * 128 * MEL + (size_t)y * 128;

    bf16x8 sA[4], sB[4];
    auto STAGE = [&](int kt) {
#pragma unroll
        for (int i = 0; i < 4; ++i) {
            int idx = i * 256 + tid;
            int row = idx >> 3, c8 = (idx & 7) * 8;
            sA[i] = *(const bf16x8*)(A + (size_t)row * DMODEL + kt * 64 + c8);
            sB[i] = *(const bf16x8*)(B + (size_t)row * DMODEL + kt * 64 + c8);
        }
    };

    STAGE(0);
    f32x4 acc[4][4];
#pragma unroll
    for (int m = 0; m < 4; ++m)
#pragma unroll
        for (int n = 0; n < 4; ++n) acc[m][n] = (f32x4){0.f, 0.f, 0.f, 0.f};

    for (int kt = 0; kt < 4; ++kt) {
        __syncthreads();
#pragma unroll
        for (int i = 0; i < 4; ++i) {
            int idx = i * 256 + tid;
            int row = idx >> 3, c8 = (idx & 7) * 8;
            *(bf16x8*)&As[row * 72 + c8] = sA[i];
            *(bf16x8*)&Bs[row * 72 + c8] = sB[i];
        }
        __syncthreads();
        if (kt < 3) STAGE(kt + 1);
#pragma unroll
        for (int kt2 = 0; kt2 < 2; ++kt2) {
            bf16x8 af[4], bfr[4];
#pragma unroll
            for (int m = 0; m < 4; ++m)
                af[m] = *(const bf16x8*)&As[(64 * wr + 16 * m + lr) * 72 + kt2 * 32 + 8 * lk];
#pragma unroll
            for (int n = 0; n < 4; ++n)
                bfr[n] = *(const bf16x8*)&Bs[(64 * wc + 16 * n + lr) * 72 + kt2 * 32 + 8 * lk];
#pragma unroll
            for (int m = 0; m < 4; ++m)
#pragma unroll
                for (int n = 0; n < 4; ++n)
                    acc[m][n] = __builtin_amdgcn_mfma_f32_16x16x32_bf16(af[m], bfr[n], acc[m][n], 0, 0, 0);
        }
    }

    // per-thread mel-mask for its 4 columns (fixed across rows)
    bool msk[4];
#pragma unroll
    for (int n = 0; n < 4; ++n)
        msk[n] = mel_mask[z * MEL + y * 128 + 64 * wc + 16 * n + lr] != 0;

    // f32 epilogue via LDS, two 64-row halves; masked+scaled; partials per half
    __syncthreads();
    float* Cs = (float*)SMEM;
#pragma unroll
    for (int half = 0; half < 2; ++half) {
        if (wr == half) {
#pragma unroll
            for (int m = 0; m < 4; ++m)
#pragma unroll
                for (int n = 0; n < 4; ++n)
#pragma unroll
                    for (int r = 0; r < 4; ++r)
                        Cs[(16 * m + 4 * lk + r) * 132 + 64 * wc + 16 * n + lr] =
                            msk[n] ? -1e30f : acc[m][n][r] * 0.0625f;
        }
        __syncthreads();
#pragma unroll
        for (int i = 0; i < 8; ++i) {
            int idx = i * 256 + tid;
            int row = idx >> 5, c4 = (idx & 31) * 4;
            *(f32x4*)&Cw[(size_t)(half * 64 + row) * MEL + c4] = *(const f32x4*)&Cs[row * 132 + c4];
        }
        // softmax partials: row = tid>>2, 4 threads/row, 32 cols each
        {
            const int rrow = tid >> 2, seg = tid & 3;
            const f32x4* crow = (const f32x4*)(Cs + rrow * 132 + seg * 32);
            float m8 = -3.0e38f;
#pragma unroll
            for (int jj = 0; jj < 8; ++jj) {
                f32x4 v = crow[jj];
#pragma unroll
                for (int e = 0; e < 4; ++e) m8 = fmaxf(m8, v[e]);
            }
            m8 = fmaxf(m8, __shfl_xor(m8, 1));
            m8 = fmaxf(m8, __shfl_xor(m8, 2));
            float s8 = 0.f;
#pragma unroll
            for (int jj = 0; jj < 8; ++jj) {
                f32x4 v = crow[jj];
#pragma unroll
                for (int e = 0; e < 4; ++e) s8 += __expf(v[e] - m8);
            }
            s8 += __shfl_xor(s8, 1);
            s8 += __shfl_xor(s8, 2);
            if (seg == 0) {
                int grow = z * SRC + x * 128 + half * 64 + rrow;
                pmax[y * 8192 + grow] = m8;
                psum[y * 8192 + grow] = s8;
            }
        }
        __syncthreads();
    }
}

// ---- combine 16 partials per row -> M, inv=1/Z (src-masked) ----
__global__ __launch_bounds__(512)
void rowred_kernel(const float* __restrict__ pmax, const float* __restrict__ psum,
                   const int* __restrict__ src_mask,
                   float* __restrict__ Mrow, float* __restrict__ Minv) {
    const int row = blockIdx.x * 512 + threadIdx.x;    // 0..8191
    float M = -3.0e38f;
#pragma unroll
    for (int i = 0; i < 16; ++i) M = fmaxf(M, pmax[i * 8192 + row]);
    float Z = 0.f;
#pragma unroll
    for (int i = 0; i < 16; ++i)
        Z += psum[i * 8192 + row] * __expf(pmax[i * 8192 + row] - M);
    Mrow[row] = M;
    Minv[row] = (src_mask[row] || !(Z > 0.f)) ? 0.f : 1.f / Z;
}

// ============================================================================
// pv_ln: softmax-apply fused into A-stage (writes attn f32 in-place),
// PV GEMM, fused LayerNorm. BM=32, BN=256, BK=64, 512 thr, grid 256 XCD-affine.
// ============================================================================
__global__ __launch_bounds__(512)
void pv_ln_kernel(float* __restrict__ attn, const short* __restrict__ vt,
                  const float* __restrict__ gamma, const float* __restrict__ beta,
                  const float* __restrict__ Mrow, const float* __restrict__ Minv,
                  float* __restrict__ out) {
    __shared__ char SMEM[42496];
    short* As = (short*)SMEM;                    // [32][72]
    short* Bs = (short*)(SMEM + 4608);           // [256][72]
    float* red = (float*)(SMEM + 41472);         // [2][32][4]
    float* Ost = (float*)(SMEM + 4608);          // [32][260] (aliases Bs)

    const int tid = threadIdx.x;
    const int lane = tid & 63, w = tid >> 6;
    const int lr = lane & 15, lk = lane >> 4;
    const int wr = w >> 2, wc = w & 3;

    const int bid = blockIdx.x;
    const int xcd = bid & 7, j = bid >> 3;
    const int b = 2 * xcd + (j >> 4);
    const int mt = j & 15;
    const size_t row0 = (size_t)mt * 32;

    float* A = attn + (size_t)b * SRC * MEL + row0 * MEL;
    const short* Bv = vt + (size_t)b * DMODEL * MEL;

    float gm[4], bt[4];
#pragma unroll
    for (int n = 0; n < 4; ++n) {
        gm[n] = gamma[64 * wc + 16 * n + lr];
        bt[n] = beta[64 * wc + 16 * n + lr];
    }

    const int a_row = tid >> 4, a_c4 = (tid & 15) * 4;
    const float Mr = Mrow[(size_t)b * SRC + row0 + a_row];
    const float Iv = Minv[(size_t)b * SRC + row0 + a_row];

    f32x4 sAv; bf16x8 sB[4];
    auto STAGE = [&](int kt) {
        sAv = *(const f32x4*)(A + (size_t)a_row * MEL + kt * 64 + a_c4);
#pragma unroll
        for (int i = 0; i < 4; ++i) {
            int idx = i * 512 + tid;
            int row = idx >> 3, c8 = (idx & 7) * 8;
            sB[i] = *(const bf16x8*)(Bv + (size_t)row * MEL + kt * 64 + c8);
        }
    };

    STAGE(0);
    f32x4 acc[4];
#pragma unroll
    for (int n = 0; n < 4; ++n) acc[n] = (f32x4){0.f, 0.f, 0.f, 0.f};

    for (int kt = 0; kt < MEL / 64; ++kt) {
        __syncthreads();
        {
            // softmax-apply: p = exp(S - M) * inv; write attn f32 in-place + LDS bf16
            f32x4 p;
#pragma unroll
            for (int e = 0; e < 4; ++e) p[e] = __expf(sAv[e] - Mr) * Iv;
            *(f32x4*)(A + (size_t)a_row * MEL + kt * 64 + a_c4) = p;
            short4v a4 = { f2bf(p[0]), f2bf(p[1]), f2bf(p[2]), f2bf(p[3]) };
            *(short4v*)&As[a_row * 72 + a_c4] = a4;
#pragma unroll
            for (int i = 0; i < 4; ++i) {
                int idx = i * 512 + tid;
                int row = idx >> 3, c8 = (idx & 7) * 8;
                *(bf16x8*)&Bs[row * 72 + c8] = sB[i];
            }
        }
        __syncthreads();
        if (kt + 1 < MEL / 64) STAGE(kt + 1);
#pragma unroll
        for (int kt2 = 0; kt2 < 2; ++kt2) {
            bf16x8 af = *(const bf16x8*)&As[(16 * wr + lr) * 72 + kt2 * 32 + 8 * lk];
#pragma unroll
            for (int n = 0; n < 4; ++n) {
                bf16x8 bfr = *(const bf16x8*)&Bs[(64 * wc + 16 * n + lr) * 72 + kt2 * 32 + 8 * lk];
                acc[n] = __builtin_amdgcn_mfma_f32_16x16x32_bf16(af, bfr, acc[n], 0, 0, 0);
            }
        }
    }

    // LayerNorm: thread holds rows {16wr+4lk+r}, cols {64wc+16n+lr}
    float s1[4] = {0.f, 0.f, 0.f, 0.f}, s2[4] = {0.f, 0.f, 0.f, 0.f};
#pragma unroll
    for (int n = 0; n < 4; ++n)
#pragma unroll
        for (int r = 0; r < 4; ++r) {
            s1[r] += acc[n][r];
            s2[r] += acc[n][r] * acc[n][r];
        }
#pragma unroll
    for (int off = 8; off; off >>= 1)
#pragma unroll
        for (int r = 0; r < 4; ++r) {
            s1[r] += __shfl_xor(s1[r], off);
            s2[r] += __shfl_xor(s2[r], off);
        }
    __syncthreads();
    if (lr == 0) {
#pragma unroll
        for (int r = 0; r < 4; ++r) {
            red[(16 * wr + 4 * lk + r) * 4 + wc] = s1[r];
            red[128 + (16 * wr + 4 * lk + r) * 4 + wc] = s2[r];
        }
    }
    __syncthreads();
    float mu[4], rsig[4];
#pragma unroll
    for (int r = 0; r < 4; ++r) {
        int rowi = 16 * wr + 4 * lk + r;
        float S1 = red[rowi * 4 + 0] + red[rowi * 4 + 1] + red[rowi * 4 + 2] + red[rowi * 4 + 3];
        float S2 = red[128 + rowi * 4 + 0] + red[128 + rowi * 4 + 1] +
                   red[128 + rowi * 4 + 2] + red[128 + rowi * 4 + 3];
        mu[r] = S1 * (1.f / DMODEL);
        rsig[r] = rsqrtf(S2 * (1.f / DMODEL) - mu[r] * mu[r] + 1e-5f);
    }
    __syncthreads();
#pragma unroll
    for (int n = 0; n < 4; ++n)
#pragma unroll
        for (int r = 0; r < 4; ++r)
            Ost[(16 * wr + 4 * lk + r) * 260 + 64 * wc + 16 * n + lr] =
                (acc[n][r] - mu[r]) * rsig[r] * gm[n] + bt[n];
    __syncthreads();
#pragma unroll
    for (int i = 0; i < 4; ++i) {
        int idx = i * 512 + tid;
        int row = idx >> 6, c4 = (idx & 63) * 4;
        *(f32x4*)&out[((size_t)b * SRC + row0 + row) * DMODEL + c4] =
            *(const f32x4*)&Ost[row * 260 + c4];
    }
}

extern "C" void kernel_launch(void* const* d_in, const int* in_sizes, int n_in,
                              void* d_out, int out_size, void* d_ws, size_t ws_size,
                              hipStream_t stream) {
    const float* mel      = (const float*)d_in[0];
    const float* text     = (const float*)d_in[1];
    const int*   mel_mask = (const int*)d_in[2];
    const int*   src_mask = (const int*)d_in[3];
    const float* Wq       = (const float*)d_in[4];
    const float* Wk       = (const float*)d_in[5];
    const float* Wv       = (const float*)d_in[6];
    const float* gamma    = (const float*)d_in[7];
    const float* beta     = (const float*)d_in[8];

    float* out  = (float*)d_out;
    float* attn = out + (size_t)BATCH * SRC * DMODEL;   // [16][512][2048] f32

    short* qbf = (short*)d_ws;                          // [8192][256] bf16
    short* kbf = qbf + (size_t)BATCH * SRC * DMODEL;    // [32768][256] bf16
    short* vt  = kbf + (size_t)BATCH * MEL * DMODEL;    // [16][256][2048] bf16
    float* pmax = (float*)(vt + (size_t)BATCH * DMODEL * MEL);  // [16][8192]
    float* psum = pmax + 16 * 8192;                             // [16][8192]
    float* Mrow = psum + 16 * 8192;                             // [8192]
    float* Minv = Mrow + 8192;                                  // [8192]

    proj_all_kernel<<<1152, 256, 0, stream>>>(mel, text, Wq, Wk, Wv, qbf, kbf, vt);
    sgemm_kernel<<<1024, 256, 0, stream>>>(qbf, kbf, mel_mask, attn, pmax, psum);
    rowred_kernel<<<16, 512, 0, stream>>>(pmax, psum, src_mask, Mrow, Minv);
    pv_ln_kernel<<<256, 512, 0, stream>>>(attn, vt, gamma, beta, Mrow, Minv, out);
}